// Round 12
// baseline (221.785 us; speedup 1.0000x reference)
//
#include <hip/hip_runtime.h>

// B=16, T=256, C=6, E=512, H=8, hd=64.
// Inputs fp32; OUTPUT fp32. Compute in bf16 MFMA; biases added in fp32.
//
// Round 16: THE GPU WAS 25% IDLE.  The ws-capacity loop picked NB=4 ->
// qkv_attn launched 192 blocks on 256 CUs (occupancy counter 20.6% =
// 192*8/8192), serialized into 4 slabs.  Fix: eliminate the xbf workspace
// tensor by reading X as fp32 INSIDE qkv_attn (reg-staged: f32x4 loads ->
// f2b -> ds_write_b128 into the SAME swizzled LDS layout; read side
// unchanged; W stays on gl_lds).  Workspace = W + y only -> NB=8 needs
// exactly the bytes NB=4 needed before (guaranteed fit) -> 384 blocks per
// dispatch (GPU full), nslab=2, and cvt_x is deleted.  Same f2b RNE ->
// bit-identical numerics.  Attn phase = round-15 verbatim (LDS 80 KB).

typedef unsigned short u16;
typedef short bf16x8 __attribute__((ext_vector_type(8)));   // 8 bf16 = 4 VGPRs
typedef float f32x4 __attribute__((ext_vector_type(4)));
typedef u16 u16x4 __attribute__((ext_vector_type(4)));
typedef u16 u16x8 __attribute__((ext_vector_type(8)));

#define MFMA16(a, b, c) __builtin_amdgcn_mfma_f32_16x16x32_bf16((a), (b), (c), 0, 0, 0)

__device__ __forceinline__ u16 f2b(float f) {
  union { float f; unsigned u; } v; v.f = f;
  unsigned r = v.u + 0x7fffu + ((v.u >> 16) & 1u);   // RNE (finite inputs)
  return (u16)(r >> 16);
}
__device__ __forceinline__ void gl_lds16(const void* g, void* l) {
  __builtin_amdgcn_global_load_lds(
      (const __attribute__((address_space(1))) void*)g,
      (__attribute__((address_space(3))) void*)l, 16, 0, 0);
}

// ---------------------------------------------------------------------------
// fp32 -> bf16 weight converter (once per launch; x is converted in-kernel).
// ---------------------------------------------------------------------------
__global__ void cvt_w(const float* W0, const float* W1, const float* W2,
                      const float* W3, u16* dst) {
  const float* src = (blockIdx.y == 0) ? W0 : (blockIdx.y == 1) ? W1
                   : (blockIdx.y == 2) ? W2 : W3;
  const int idx = (blockIdx.x * 256 + threadIdx.x) * 4;
  f32x4 v = *(const f32x4*)(src + idx);
  u16x4 o; o.x = f2b(v.x); o.y = f2b(v.y); o.z = f2b(v.z); o.w = f2b(v.w);
  *(u16x4*)(dst + (size_t)blockIdx.y * 262144 + idx) = o;
}

// ---------------------------------------------------------------------------
// Fused QKV + causal attention.  One block per (b,h,c); 512 thr = 8 waves.
// GEMM split (round 15): wave wv = (g = wv>>1: rows [64g,64g+64)) x
//                        (ch = wv&1: per-tensor cols [32ch,32ch+32)).
// Staged tile (28 KB/buffer, chunk-swizzled 64-B rows):
//   X rows 0..255 -- written in-kernel from fp32 (f2b + ds_write_b128);
//   W rows 256..447 (sr = ch*96 + tau*32 + nn) -- gl_lds from wbf.
// Attn split: wave wv owns q-tiles {wv, 15-wv}.
// LDS = 80 KB (1 block/CU, register-gated):
//   staging 2 x 28 KB at [0, 57344)   (phase 1 only)
//   [    0,16384) Ks   128 x 128 B    (pass keys, XOR-swizzled)
//   [16384,32768) Vts   64 x 256 B    (V^T, XOR-swizzled)
//   [32768,65536) Qs   256 x 128 B    (all Q, XOR-swizzled, written once)
//   [65536,81920) Pw   8 x 16 x 128 B (per-wave P scratch)
// ---------------------------------------------------------------------------
#define STAGE_X(k, bi) do { \
  const float* xs_ = xsrc + (k) * 32; \
  f32x4 x0_ = *(const f32x4*)(xs_);      f32x4 x1_ = *(const f32x4*)(xs_ + 4); \
  f32x4 x2_ = *(const f32x4*)(xs_ + 8);  f32x4 x3_ = *(const f32x4*)(xs_ + 12); \
  u16x8 p0_, p1_; \
  p0_[0]=f2b(x0_.x); p0_[1]=f2b(x0_.y); p0_[2]=f2b(x0_.z); p0_[3]=f2b(x0_.w); \
  p0_[4]=f2b(x1_.x); p0_[5]=f2b(x1_.y); p0_[6]=f2b(x1_.z); p0_[7]=f2b(x1_.w); \
  p1_[0]=f2b(x2_.x); p1_[1]=f2b(x2_.y); p1_[2]=f2b(x2_.z); p1_[3]=f2b(x2_.w); \
  p1_[4]=f2b(x3_.x); p1_[5]=f2b(x3_.y); p1_[6]=f2b(x3_.z); p1_[7]=f2b(x3_.w); \
  *(u16x8*)(Sb + (bi) * 28672 + xw0) = p0_; \
  *(u16x8*)(Sb + (bi) * 28672 + xw1) = p1_; \
} while (0)

#define STAGE_W(k, bi) do { \
  gl_lds16(wsrc[0] + (k) * 64, Sb + (bi) * 28672 + wfl[0]); \
  if (tid < 256) gl_lds16(wsrc[1] + (k) * 64, Sb + (bi) * 28672 + wfl[1]); \
} while (0)

#define FENCE() do { \
  asm volatile("s_waitcnt vmcnt(0) lgkmcnt(0)" ::: "memory"); \
  __builtin_amdgcn_s_barrier(); \
} while (0)

__global__ __launch_bounds__(512, 2) void qkv_attn(
    const float* __restrict__ xf, const u16* __restrict__ wbf,
    const float* __restrict__ bq, const float* __restrict__ bk,
    const float* __restrict__ bv, u16* __restrict__ y_ws)
{
  const int blk = blockIdx.x;            // (b*8 + h)*6 + c  (b slab-local)
  const int b   = blk / 48;
  const int h   = (blk / 6) % 8;
  const int c   = blk % 6;

  __shared__ u16 LDS[40960];             // 80 KB
  char* Ksb  = (char*)LDS;               // Ks  (16 KB)
  char* Vtsb = (char*)LDS + 16384;       // Vts (16 KB)
  char* Qsb  = (char*)LDS + 32768;       // Qs  (32 KB)
  char* Sb   = (char*)LDS;               // staging base (2 x 28 KB)

  const int tid  = threadIdx.x;
  const int lane = tid & 63;
  const int wv   = tid >> 6;
  const int r    = lane & 15;
  const int qd   = lane >> 4;
  const int g    = wv >> 1;              // row-group 0..3
  const int ch   = wv & 1;               // col-half 0..1
  const int tiles[2] = { wv, 15 - wv };
  char* Pw = (char*)LDS + 65536 + wv * 2048;   // per-wave 16 x 128 B

  // ---- X staging mapping: thread covers row xrow, k-halves [16*xhalf, +16).
  // Stored chunk q holds global chunk (q - row>>1)&3  <=>  global chunk gq
  // stored at (gq + row>>1)&3.
  const int xrow  = tid >> 1;
  const int xhalf = tid & 1;
  const float* xsrc = xf + ((size_t)(b * 256 + xrow) * 6 + c) * 512 + xhalf * 16;
  const int xw0 = xrow * 64 + (((xhalf * 2    ) + (xrow >> 1)) & 3) * 16;
  const int xw1 = xrow * 64 + (((xhalf * 2 + 1) + (xrow >> 1)) & 3) * 16;

  // ---- W staging (gl_lds): staged rows 256..447, sr = chw*96 + tau*32 + nn.
  const char* wsrc[2]; int wfl[2];
  #pragma unroll
  for (int j = 0; j < 2; ++j) {
    const int idx  = j * 512 + tid;
    const int flat = 16384 + idx * 16;
    const int row  = flat >> 6;                       // 256..463 (>=448 inert)
    const int gc   = (((flat >> 4) & 3) - (row >> 1)) & 3;
    const int sr   = row - 256;
    const int chw  = sr / 96;
    const int rem  = sr - chw * 96;
    const int tau  = rem >> 5;
    const int nn   = rem & 31;
    wfl[j]  = flat;
    wsrc[j] = (const char*)wbf + (size_t)tau * 524288 +
              (size_t)(h * 64 + chw * 32 + nn) * 1024 + gc * 16;
  }

  // fragment LDS byte offsets within one staging buffer (loop-invariant)
  int aoff[4], boff[3][2];
  #pragma unroll
  for (int mt = 0; mt < 4; ++mt) {
    const int row = g * 64 + mt * 16 + r;
    aoff[mt] = row * 64 + ((qd + (row >> 1)) & 3) * 16;
  }
  #pragma unroll
  for (int tau = 0; tau < 3; ++tau)
    #pragma unroll
    for (int nt = 0; nt < 2; ++nt) {
      const int row = 256 + ch * 96 + tau * 32 + nt * 16 + r;
      boff[tau][nt] = row * 64 + ((qd + (row >> 1)) & 3) * 16;
    }

  f32x4 acc[3][4][2] = {};   // [q,k,v][mt][nt]

  // ---- Phase 1: GEMM over K=512, BK=32, double-buffered (X reg-staged) ----
  STAGE_X(0, 0); STAGE_W(0, 0);
  FENCE();

  #pragma unroll 2
  for (int kt = 0; kt < 16; ++kt) {
    const int cur = kt & 1;
    if (kt < 15) { STAGE_X(kt + 1, cur ^ 1); STAGE_W(kt + 1, cur ^ 1); }

    char* Sc = Sb + cur * 28672;
    bf16x8 af[4], bfr[3][2];
    #pragma unroll
    for (int mt = 0; mt < 4; ++mt)
      af[mt] = *(const bf16x8*)(Sc + aoff[mt]);
    #pragma unroll
    for (int tau = 0; tau < 3; ++tau)
      #pragma unroll
      for (int nt = 0; nt < 2; ++nt)
        bfr[tau][nt] = *(const bf16x8*)(Sc + boff[tau][nt]);

    #pragma unroll
    for (int tau = 0; tau < 3; ++tau)
      #pragma unroll
      for (int mt = 0; mt < 4; ++mt)
        #pragma unroll
        for (int nt = 0; nt < 2; ++nt)
          acc[tau][mt][nt] = MFMA16(af[mt], bfr[tau][nt], acc[tau][mt][nt]);

    if (kt < 15) FENCE();
  }
  __syncthreads();   // staging region free for Ks/Vts/Qs

  // ---- biases (fp32); wave covers per-tensor cols ch*32 + nt*16 + r ----
  float bqv[2], bkv[2], bvv[2];
  #pragma unroll
  for (int nt = 0; nt < 2; ++nt) {
    const int col = h * 64 + ch * 32 + nt * 16 + r;
    bqv[nt] = bq[col]; bkv[nt] = bk[col]; bvv[nt] = bv[col];
  }

  const int lo0 = ( qd      ^ (r & 7)) << 4;   // granule kc*4+qd, kc=0
  const int lo1 = ((4 + qd) ^ (r & 7)) << 4;   // kc=1

  // ---- Q -> shared Qs (once).  Qs[t][col], 128-B rows, granule ^= t&7 ----
  #pragma unroll
  for (int mt = 0; mt < 4; ++mt)
    #pragma unroll
    for (int nt = 0; nt < 2; ++nt)
      #pragma unroll
      for (int rr = 0; rr < 4; ++rr) {
        const int t   = g * 64 + mt * 16 + qd * 4 + rr;
        const int col = ch * 32 + nt * 16 + r;
        const int qb  = t * 128 + (((col >> 3) ^ (t & 7)) << 4) + (r & 7) * 2;
        *(u16*)(Qsb + qb) = f2b(acc[0][mt][nt][rr] + bqv[nt]);
      }

  f32x4 o_acc[2][4] = {};
  float l_acc[2][4] = {{0.f,0.f,0.f,0.f},{0.f,0.f,0.f,0.f}};

  // ---- Phases 2+3: two 128-key passes (sc unrolled: rule #20) ----
  #pragma unroll
  for (int sc = 0; sc < 2; ++sc) {
    if (sc) __syncthreads();           // pass-0 reads done before overwrite

    if ((g >> 1) == sc) {              // wave-uniform: owning waves write K/V
      #pragma unroll
      for (int mt = 0; mt < 4; ++mt) {
        const int tl0 = g * 64 + mt * 16 + qd * 4 - sc * 128;   // 0..124, %4==0
        #pragma unroll
        for (int nt = 0; nt < 2; ++nt) {
          u16x4 pv;
          #pragma unroll
          for (int rr = 0; rr < 4; ++rr)
            ((u16*)&pv)[rr] = f2b(acc[2][mt][nt][rr] + bvv[nt]);
          const int d  = ch * 32 + nt * 16 + r;
          const int vb = d * 256 + (((tl0 >> 3) ^ (r & 7)) << 4) + (tl0 & 7) * 2;
          *(u16x4*)(Vtsb + vb) = pv;
        }
        #pragma unroll
        for (int nt = 0; nt < 2; ++nt)
          #pragma unroll
          for (int rr = 0; rr < 4; ++rr) {
            const int tl  = tl0 + rr;
            const int col = ch * 32 + nt * 16 + r;
            const int kb  = tl * 128 + (((col >> 3) ^ (tl & 7)) << 4) + (r & 7) * 2;
            *(u16*)(Ksb + kb) = f2b(acc[1][mt][nt][rr] + bkv[nt]);
          }
      }
    }
    __syncthreads();

    // attention against this pass's keys
    #pragma unroll
    for (int ti = 0; ti < 2; ++ti) {
      if (sc == 1 && ti == 0) continue;   // q-tiles 0..7 complete in pass 0
      const int mt  = tiles[ti];
      const int i0  = mt * 16;
      const int nch = (mt >> 2) + 1;      // total 64-chunks this tile needs

      bf16x8 qf[2];
      qf[0] = *(const bf16x8*)(Qsb + (i0 + r) * 128 + lo0);
      qf[1] = *(const bf16x8*)(Qsb + (i0 + r) * 128 + lo1);

      #pragma unroll
      for (int jcl = 0; jcl < 2; ++jcl) {
        const int jcg = sc * 2 + jcl;
        if (jcg >= nch) continue;         // wave-uniform skip
        const int j0l = jcl * 64;         // key offset within this pass
        const int j0g = jcg * 64;         // global key offset (causal mask)

        f32x4 s[4] = {};
        #pragma unroll
        for (int nt = 0; nt < 4; ++nt) {
          const int krow = j0l + nt * 16 + r;
          bf16x8 kf0 = *(const bf16x8*)(Ksb + krow * 128 + lo0);
          s[nt] = MFMA16(qf[0], kf0, s[nt]);
          bf16x8 kf1 = *(const bf16x8*)(Ksb + krow * 128 + lo1);
          s[nt] = MFMA16(qf[1], kf1, s[nt]);
        }

        #pragma unroll
        for (int nt = 0; nt < 4; ++nt)
          #pragma unroll
          for (int rr = 0; rr < 4; ++rr) {
            const int i = i0 + qd * 4 + rr;
            const int j = j0g + nt * 16 + r;
            float p = __builtin_exp2f(fminf(s[nt][rr], 500.f) *
                                      0.1803368801111244f);  // *(1/8)*log2(e)
            if (j > i) p = 0.f;
            l_acc[ti][rr] += p;
            const int prow = qd * 4 + rr;
            const int pb = prow * 128 +
                (((nt * 2 + (r >> 3)) ^ (prow & 7)) << 4) + (r & 7) * 2;
            *(u16*)(Pw + pb) = f2b(p);
          }
        asm volatile("s_waitcnt lgkmcnt(0)" ::: "memory");

        bf16x8 pf[2];
        pf[0] = *(const bf16x8*)(Pw + r * 128 + lo0);
        pf[1] = *(const bf16x8*)(Pw + r * 128 + lo1);
        #pragma unroll
        for (int ntd = 0; ntd < 4; ++ntd) {
          const int vrow = ntd * 16 + r;
          bf16x8 vf0 = *(const bf16x8*)(Vtsb + vrow * 256 +
              ((((j0l >> 3) + qd) ^ (r & 7)) << 4));
          o_acc[ti][ntd] = MFMA16(pf[0], vf0, o_acc[ti][ntd]);
          bf16x8 vf1 = *(const bf16x8*)(Vtsb + vrow * 256 +
              ((((j0l >> 3) + 4 + qd) ^ (r & 7)) << 4));
          o_acc[ti][ntd] = MFMA16(pf[1], vf1, o_acc[ti][ntd]);
        }
      }
    }
  }

  // ---- output: y layout [b][t][h][c][d] (faithful to the torch view) ----
  const size_t obase = ((size_t)b * 256) * 3072 + h * 384 + c * 64;
  #pragma unroll
  for (int ti = 0; ti < 2; ++ti) {
    const int i0 = tiles[ti] * 16;
    float linv[4];
    #pragma unroll
    for (int rr = 0; rr < 4; ++rr) {
      float sum = l_acc[ti][rr];
      sum += __shfl_xor(sum, 1, 16);
      sum += __shfl_xor(sum, 2, 16);
      sum += __shfl_xor(sum, 4, 16);
      sum += __shfl_xor(sum, 8, 16);
      linv[rr] = 1.f / sum;
    }
    #pragma unroll
    for (int ntd = 0; ntd < 4; ++ntd)
      #pragma unroll
      for (int rr = 0; rr < 4; ++rr) {
        const int t = i0 + qd * 4 + rr;
        const int d = ntd * 16 + r;
        y_ws[obase + (size_t)t * 3072 + d] = f2b(o_acc[ti][ntd][rr] * linv[rr]);
      }
  }
}

// ---------------------------------------------------------------------------
// BT-GEMM (round-0 verbatim, used for the output projection only).
// ---------------------------------------------------------------------------
__global__ __launch_bounds__(256, 3) void gemm_bt(
    const u16* __restrict__ A,
    const u16* W0, const u16* W1, const u16* W2,
    const float* bs0, const float* bs1, const float* bs2,
    u16* O0, u16* O1, u16* O2,
    float* OF,
    int qkv_mode)
{
  const int z = blockIdx.z;
  const u16* W    = (z == 0) ? W0 : (z == 1) ? W1 : W2;
  const float* bs = (z == 0) ? bs0 : (z == 1) ? bs1 : bs2;
  u16* O          = (z == 0) ? O0 : (z == 1) ? O1 : O2;

  const int m0 = blockIdx.x * 128;
  const int n0 = blockIdx.y * 128;

  __shared__ u16 As[128 * 32];   // 8 KB, 64B rows, chunk swizzle (q + (row>>1)) & 3
  __shared__ u16 Bs[128 * 32];

  const int tid  = threadIdx.x;
  const int lane = tid & 63;
  const int wv   = tid >> 6;
  const int r    = lane & 15;
  const int qd   = lane >> 4;
  const int wm   = (wv & 1) * 64;
  const int wn   = (wv >> 1) * 64;

  f32x4 acc[4][4] = {};

  for (int k0 = 0; k0 < 512; k0 += 32) {
    __syncthreads();
    #pragma unroll
    for (int it = 0; it < 2; ++it) {
      const int flat = (it * 256 + tid) * 16;       // byte offset in 8KB tile
      const int row  = flat >> 6;                   // 64 B per row
      const int swc  = (flat >> 4) & 3;
      const int gc   = (swc - (row >> 1)) & 3;      // un-swizzle for global side
      gl_lds16((const char*)A + (size_t)(m0 + row) * 1024 + k0 * 2 + gc * 16,
               (char*)As + flat);
      gl_lds16((const char*)W + (size_t)(n0 + row) * 1024 + k0 * 2 + gc * 16,
               (char*)Bs + flat);
    }
    __syncthreads();

    bf16x8 af[4], bf[4];
    #pragma unroll
    for (int mt = 0; mt < 4; ++mt) {
      const int row = wm + mt * 16 + r;
      const int sw  = (qd + (row >> 1)) & 3;
      af[mt] = *(const bf16x8*)((const char*)As + row * 64 + sw * 16);
    }
    #pragma unroll
    for (int nt = 0; nt < 4; ++nt) {
      const int row = wn + nt * 16 + r;
      const int sw  = (qd + (row >> 1)) & 3;
      bf[nt] = *(const bf16x8*)((const char*)Bs + row * 64 + sw * 16);
    }
    #pragma unroll
    for (int mt = 0; mt < 4; ++mt)
      #pragma unroll
      for (int nt = 0; nt < 4; ++nt)
        acc[mt][nt] = MFMA16(af[mt], bf[nt], acc[mt][nt]);
  }

  float bv[4];
  #pragma unroll
  for (int nt = 0; nt < 4; ++nt) bv[nt] = bs[n0 + wn + nt * 16 + r];

  if (qkv_mode) {
    #pragma unroll
    for (int mt = 0; mt < 4; ++mt) {
      #pragma unroll
      for (int rr = 0; rr < 4; ++rr) {
        const int m   = m0 + wm + mt * 16 + qd * 4 + rr;   // (b*T+t)*C + c
        const int b   = m / 1536;
        const int rem = m - b * 1536;
        const int t   = rem / 6;
        const int c   = rem - t * 6;
        #pragma unroll
        for (int nt = 0; nt < 4; ++nt) {
          const int f = n0 + wn + nt * 16 + r;             // h*64 + d
          const int hh = f >> 6;
          const int d = f & 63;
          const size_t addr = ((((size_t)b * 8 + hh) * 6 + c) * 256 + t) * 64 + d;
          O[addr] = f2b(acc[mt][nt][rr] + bv[nt]);
        }
      }
    }
  } else {
    #pragma unroll
    for (int mt = 0; mt < 4; ++mt) {
      #pragma unroll
      for (int rr = 0; rr < 4; ++rr) {
        const int m = m0 + wm + mt * 16 + qd * 4 + rr;
        #pragma unroll
        for (int nt = 0; nt < 4; ++nt) {
          const int f = n0 + wn + nt * 16 + r;
          OF[(size_t)m * 512 + f] = acc[mt][nt][rr] + bv[nt];   // fp32 output
        }
      }
    }
  }
}

// ---------------------------------------------------------------------------
extern "C" void kernel_launch(void* const* d_in, const int* in_sizes, int n_in,
                              void* d_out, int out_size, void* d_ws, size_t ws_size,
                              hipStream_t stream) {
  const float* x  = (const float*)d_in[0];
  const float* Wq = (const float*)d_in[1];
  const float* bq = (const float*)d_in[2];
  const float* Wk = (const float*)d_in[3];
  const float* bk = (const float*)d_in[4];
  const float* Wv = (const float*)d_in[5];
  const float* bv = (const float*)d_in[6];
  const float* Wp = (const float*)d_in[7];
  const float* bp = (const float*)d_in[8];
  float* out = (float*)d_out;                        // fp32 output

  const size_t PER_B = 256 * 6 * 512;       // 786432 elems per tensor per batch
  const size_t WSEG  = 4 * 262144;          // converted weights: Wq,Wk,Wv,Wp

  // Workspace = weights + y only (x is read fp32 in-kernel).
  int NB = 16;
  while (NB > 1 && (WSEG + (size_t)NB * PER_B) * 2 > ws_size) NB >>= 1;

  u16* wbf = (u16*)d_ws;                    // Wq | Wk | Wv | Wp (bf16)
  u16* Wpb = wbf + 3 * 262144;
  u16* y_ws = wbf + WSEG;

  cvt_w<<<dim3(256, 4), 256, 0, stream>>>(Wq, Wk, Wv, Wp, wbf);

  const int nslab = 16 / NB;
  for (int s = 0; s < nslab; ++s) {
    const float* x_s  = x   + (size_t)s * NB * PER_B;
    float*      out_s = out + (size_t)s * NB * PER_B;
    qkv_attn<<<dim3(NB * 48), 512, 0, stream>>>(x_s, wbf, bq, bk, bv, y_ws);
    gemm_bt<<<dim3(NB * 12, 4, 1), 256, 0, stream>>>(
        y_ws, Wpb, Wpb, Wpb, bp, bp, bp, nullptr, nullptr, nullptr, out_s, 0);
  }
}

// Round 13
// 199.943 us; speedup vs baseline: 1.1092x; 1.1092x over previous
//
#include <hip/hip_runtime.h>

// B=16, T=256, C=6, E=512, H=8, hd=64.
// Inputs fp32; OUTPUT fp32. Compute in bf16 MFMA; biases added in fp32.
//
// Round 17: REVERT to the session-best kernel (round-5 bench: 198.76 us).
// Post-round-5 structural changes (two-pass K/V, triple-buffered staging,
// wave re-split, NB=8 + in-kernel fp32 X) were all bench-null or negative.
// Fill analysis: 768 qkv blocks at 1 block/CU can only reach 100% fill as a
// single 768-block dispatch (= 3 x 256 CUs), which requires full-batch y
// (25.17 MB) + weights in workspace; measured ws bound is [14.68, 27.26) MB
// (NB-selection history), so that layout does not fit.  75% fill is
// structurally pinned; this kernel is the best measured configuration.
//
// Structure: fused QKV-GEMM + causal attention, one block per (b,h,c),
// 80 KB LDS (staging aliases attn buffers), XOR-swizzled Ks/Vts/Q-P scratch;
// proj via the round-0 128x128 BT-GEMM.

typedef unsigned short u16;
typedef short bf16x8 __attribute__((ext_vector_type(8)));   // 8 bf16 = 4 VGPRs
typedef float f32x4 __attribute__((ext_vector_type(4)));
typedef u16 u16x4 __attribute__((ext_vector_type(4)));

#define MFMA16(a, b, c) __builtin_amdgcn_mfma_f32_16x16x32_bf16((a), (b), (c), 0, 0, 0)

__device__ __forceinline__ u16 f2b(float f) {
  union { float f; unsigned u; } v; v.f = f;
  unsigned r = v.u + 0x7fffu + ((v.u >> 16) & 1u);   // RNE (finite inputs)
  return (u16)(r >> 16);
}
__device__ __forceinline__ void gl_lds16(const void* g, void* l) {
  __builtin_amdgcn_global_load_lds(
      (const __attribute__((address_space(1))) void*)g,
      (__attribute__((address_space(3))) void*)l, 16, 0, 0);
}

// ---------------------------------------------------------------------------
// fp32 -> bf16 converters
// ---------------------------------------------------------------------------
__global__ void cvt_w(const float* W0, const float* W1, const float* W2,
                      const float* W3, u16* dst) {
  const float* src = (blockIdx.y == 0) ? W0 : (blockIdx.y == 1) ? W1
                   : (blockIdx.y == 2) ? W2 : W3;
  const int idx = (blockIdx.x * 256 + threadIdx.x) * 4;
  f32x4 v = *(const f32x4*)(src + idx);
  u16x4 o; o.x = f2b(v.x); o.y = f2b(v.y); o.z = f2b(v.z); o.w = f2b(v.w);
  *(u16x4*)(dst + (size_t)blockIdx.y * 262144 + idx) = o;
}

__global__ void cvt_x(const float* __restrict__ src, u16* __restrict__ dst) {
  const size_t idx = ((size_t)blockIdx.x * 256 + threadIdx.x) * 4;
  f32x4 v = *(const f32x4*)(src + idx);
  u16x4 o; o.x = f2b(v.x); o.y = f2b(v.y); o.z = f2b(v.z); o.w = f2b(v.w);
  *(u16x4*)(dst + idx) = o;
}

// ---------------------------------------------------------------------------
// Fused QKV + causal attention.  One block per (b,h,c); 512 thr = 8 waves.
// Wave w owns t-tiles {w, 15-w}.  LDS = 80 KB total:
//   bytes [    0, 32768)  Ks  256 rows x 128 B  (XOR-swizzled)
//   bytes [32768, 65536)  Vts  64 rows x 512 B  (V transposed, XOR-swizzled)
//   bytes [65536, 81920)  Qs   8 waves x 16 rows x 128 B (Q then P scratch)
//   Phase-1 staging: 2 x 28 KB at bytes [0, 57344), aliases Ks+Vts.
// ---------------------------------------------------------------------------
#define STAGE(k, bi) do { \
  _Pragma("unroll") \
  for (int j_ = 0; j_ < 4; ++j_) \
    if (j_ < 3 || tid < 256) \
      gl_lds16(gsrc[j_] + (k) * 64, Sb + (bi) * 28672 + fl[j_]); \
} while (0)

__global__ __launch_bounds__(512, 2) void qkv_attn(
    const u16* __restrict__ xbf, const u16* __restrict__ wbf,
    const float* __restrict__ bq, const float* __restrict__ bk,
    const float* __restrict__ bv, u16* __restrict__ y_ws)
{
  const int blk = blockIdx.x;            // (b*8 + h)*6 + c  (b slab-local)
  const int b   = blk / 48;
  const int h   = (blk / 6) % 8;
  const int c   = blk % 6;

  __shared__ u16 LDS[40960];             // 80 KB
  char* Ksb  = (char*)LDS;               // Ks base
  char* Vtsb = (char*)LDS + 32768;       // Vts base
  char* Sb   = (char*)LDS;               // staging base (aliases Ks+Vts)

  const int tid  = threadIdx.x;
  const int lane = tid & 63;
  const int wv   = tid >> 6;
  const int r    = lane & 15;
  const int qd   = lane >> 4;
  const int tiles[2] = { wv, 15 - wv };
  char* Qw = (char*)LDS + 65536 + wv * 2048;   // per-wave 16 x 128 B

  // ---- staging source pointers (round-0 chunk swizzle: stored chunk q holds
  // global chunk (q - row>>1)&3; read side uses (qd + row>>1)&3) ----
  const char* gsrc[4]; int fl[4];
  #pragma unroll
  for (int j = 0; j < 4; ++j) {
    const int idx  = j * 512 + tid;
    const int flat = idx * 16;
    const int row  = flat >> 6;                       // 64 B per row
    const int gc   = (((flat >> 4) & 3) - (row >> 1)) & 3;
    fl[j] = flat;
    if (row < 256) {
      gsrc[j] = (const char*)xbf +
                ((size_t)(b * 256 + row) * 6 + c) * 1024 + gc * 16;
    } else {
      const int wr  = row - 256;
      const int tau = (wr >> 6) & 3;                  // masked for inactive lanes
      const int n   = wr & 63;
      gsrc[j] = (const char*)wbf + (size_t)tau * 524288 +
                (size_t)(h * 64 + n) * 1024 + gc * 16;
    }
  }

  // fragment LDS byte offsets within one staging buffer (loop-invariant)
  int aoff[2], boff[3][4];
  #pragma unroll
  for (int ti = 0; ti < 2; ++ti) {
    const int row = tiles[ti] * 16 + r;
    aoff[ti] = row * 64 + ((qd + (row >> 1)) & 3) * 16;
  }
  #pragma unroll
  for (int tau = 0; tau < 3; ++tau)
    #pragma unroll
    for (int nt = 0; nt < 4; ++nt) {
      const int row = 256 + tau * 64 + nt * 16 + r;
      boff[tau][nt] = row * 64 + ((qd + (row >> 1)) & 3) * 16;
    }

  f32x4 acc[3][2][4] = {};   // [q,k,v][tile][ntile]

  // ---- Phase 1: GEMM over K=512, BK=32, double-buffered ----
  STAGE(0, 0);
  __syncthreads();

  #pragma unroll 2
  for (int kt = 0; kt < 16; ++kt) {
    const int bi = kt & 1;
    if (kt < 15) STAGE(kt + 1, bi ^ 1);

    bf16x8 af[2], bfr[3][4];
    #pragma unroll
    for (int ti = 0; ti < 2; ++ti)
      af[ti] = *(const bf16x8*)(Sb + bi * 28672 + aoff[ti]);
    #pragma unroll
    for (int tau = 0; tau < 3; ++tau)
      #pragma unroll
      for (int nt = 0; nt < 4; ++nt)
        bfr[tau][nt] = *(const bf16x8*)(Sb + bi * 28672 + boff[tau][nt]);

    #pragma unroll
    for (int tau = 0; tau < 3; ++tau)
      #pragma unroll
      for (int ti = 0; ti < 2; ++ti)
        #pragma unroll
        for (int nt = 0; nt < 4; ++nt)
          acc[tau][ti][nt] = MFMA16(af[ti], bfr[tau][nt], acc[tau][ti][nt]);

    __syncthreads();   // drains staged kt+1; guards buffer reuse
  }
  // Phase-1 done: staging region free for Ks/Vts.

  // ---- Phase 2: K,V epilogue to LDS (bias in fp32, then f2b) ----
  float bqv[4], bkv[4], bvv[4];
  #pragma unroll
  for (int nt = 0; nt < 4; ++nt) {
    const int col = h * 64 + nt * 16 + r;
    bqv[nt] = bq[col]; bkv[nt] = bk[col]; bvv[nt] = bv[col];
  }
  #pragma unroll
  for (int ti = 0; ti < 2; ++ti)
    #pragma unroll
    for (int nt = 0; nt < 4; ++nt)
      #pragma unroll
      for (int rr = 0; rr < 4; ++rr) {
        const int trow = tiles[ti] * 16 + qd * 4 + rr;
        // Ks[trow][nt*16+r], 128-B rows, granule ^= trow&7
        const int kb = trow * 128 +
            ((((nt * 2 + (r >> 3)) ^ (trow & 7)) << 4)) + (r & 7) * 2;
        *(u16*)(Ksb + kb) = f2b(acc[1][ti][nt][rr] + bkv[nt]);
        // Vts[d = nt*16+r][t = trow], 512-B rows, granule ^= d&7 (= r&7)
        const int vb = (nt * 16 + r) * 512 +
            ((((trow >> 3) ^ (r & 7)) << 4)) + (trow & 7) * 2;
        *(u16*)(Vtsb + vb) = f2b(acc[2][ti][nt][rr] + bvv[nt]);
      }
  __syncthreads();

  // ---- Phase 3: causal attention ----
  const int lo0 = (( qd      ) ^ (r & 7)) << 4;   // granule kc*4+qd, kc=0
  const int lo1 = ((4 + qd) ^ (r & 7)) << 4;      // kc=1

  f32x4 o_acc[2][4] = {};
  float l_acc[2][4] = {{0.f,0.f,0.f,0.f},{0.f,0.f,0.f,0.f}};

  #pragma unroll
  for (int ti = 0; ti < 2; ++ti) {
    const int mt  = tiles[ti];
    const int i0  = mt * 16;
    const int nch = (mt >> 2) + 1;

    // Q bounce through per-wave scratch (wave-local; DS ops are in-order)
    #pragma unroll
    for (int nt = 0; nt < 4; ++nt)
      #pragma unroll
      for (int rr = 0; rr < 4; ++rr) {
        const int prow = qd * 4 + rr;
        const int qb = prow * 128 +
            (((nt * 2 + (r >> 3)) ^ (prow & 7)) << 4) + (r & 7) * 2;
        *(u16*)(Qw + qb) = f2b(acc[0][ti][nt][rr] + bqv[nt]);
      }
    asm volatile("s_waitcnt lgkmcnt(0)" ::: "memory");

    bf16x8 qf[2];
    qf[0] = *(const bf16x8*)(Qw + r * 128 + lo0);
    qf[1] = *(const bf16x8*)(Qw + r * 128 + lo1);
    asm volatile("s_waitcnt lgkmcnt(0)" ::: "memory");

    for (int jc = 0; jc < nch; ++jc) {   // wave-uniform chunk loop
      const int j0 = jc * 64;

      f32x4 s[4] = {};
      #pragma unroll
      for (int nt = 0; nt < 4; ++nt) {
        const int krow = j0 + nt * 16 + r;
        bf16x8 kf0 = *(const bf16x8*)(Ksb + krow * 128 + lo0);
        s[nt] = MFMA16(qf[0], kf0, s[nt]);
        bf16x8 kf1 = *(const bf16x8*)(Ksb + krow * 128 + lo1);
        s[nt] = MFMA16(qf[1], kf1, s[nt]);
      }

      #pragma unroll
      for (int nt = 0; nt < 4; ++nt)
        #pragma unroll
        for (int rr = 0; rr < 4; ++rr) {
          const int i = i0 + qd * 4 + rr;
          const int j = j0 + nt * 16 + r;
          float p = __builtin_exp2f(fminf(s[nt][rr], 500.f) *
                                    0.1803368801111244f);  // *(1/8)*log2(e)
          if (j > i) p = 0.f;
          l_acc[ti][rr] += p;
          const int prow = qd * 4 + rr;
          const int pb = prow * 128 +
              (((nt * 2 + (r >> 3)) ^ (prow & 7)) << 4) + (r & 7) * 2;
          *(u16*)(Qw + pb) = f2b(p);
        }
      asm volatile("s_waitcnt lgkmcnt(0)" ::: "memory");

      bf16x8 pf[2];
      pf[0] = *(const bf16x8*)(Qw + r * 128 + lo0);
      pf[1] = *(const bf16x8*)(Qw + r * 128 + lo1);
      #pragma unroll
      for (int ntd = 0; ntd < 4; ++ntd) {
        const int vrow = ntd * 16 + r;
        bf16x8 vf0 = *(const bf16x8*)(Vtsb + vrow * 512 + j0 * 2 + lo0);
        o_acc[ti][ntd] = MFMA16(pf[0], vf0, o_acc[ti][ntd]);
        bf16x8 vf1 = *(const bf16x8*)(Vtsb + vrow * 512 + j0 * 2 + lo1);
        o_acc[ti][ntd] = MFMA16(pf[1], vf1, o_acc[ti][ntd]);
      }
    }
  }

  // ---- output: y layout [b][t][h][c][d] (faithful to the torch reshape) ----
  const size_t obase = ((size_t)b * 256) * 3072 + h * 384 + c * 64;
  #pragma unroll
  for (int ti = 0; ti < 2; ++ti) {
    const int i0 = tiles[ti] * 16;
    float linv[4];
    #pragma unroll
    for (int rr = 0; rr < 4; ++rr) {
      float sum = l_acc[ti][rr];
      sum += __shfl_xor(sum, 1, 16);
      sum += __shfl_xor(sum, 2, 16);
      sum += __shfl_xor(sum, 4, 16);
      sum += __shfl_xor(sum, 8, 16);
      linv[rr] = 1.f / sum;
    }
    #pragma unroll
    for (int ntd = 0; ntd < 4; ++ntd)
      #pragma unroll
      for (int rr = 0; rr < 4; ++rr) {
        const int t = i0 + qd * 4 + rr;
        const int d = ntd * 16 + r;
        y_ws[obase + (size_t)t * 3072 + d] = f2b(o_acc[ti][ntd][rr] * linv[rr]);
      }
  }
}

// ---------------------------------------------------------------------------
// BT-GEMM (round-0 verbatim, used for the output projection only).
// ---------------------------------------------------------------------------
__global__ __launch_bounds__(256, 3) void gemm_bt(
    const u16* __restrict__ A,
    const u16* W0, const u16* W1, const u16* W2,
    const float* bs0, const float* bs1, const float* bs2,
    u16* O0, u16* O1, u16* O2,
    float* OF,
    int qkv_mode)
{
  const int z = blockIdx.z;
  const u16* W    = (z == 0) ? W0 : (z == 1) ? W1 : W2;
  const float* bs = (z == 0) ? bs0 : (z == 1) ? bs1 : bs2;
  u16* O          = (z == 0) ? O0 : (z == 1) ? O1 : O2;

  const int m0 = blockIdx.x * 128;
  const int n0 = blockIdx.y * 128;

  __shared__ u16 As[128 * 32];   // 8 KB, 64B rows, chunk swizzle (q + (row>>1)) & 3
  __shared__ u16 Bs[128 * 32];

  const int tid  = threadIdx.x;
  const int lane = tid & 63;
  const int wv   = tid >> 6;
  const int r    = lane & 15;
  const int qd   = lane >> 4;
  const int wm   = (wv & 1) * 64;
  const int wn   = (wv >> 1) * 64;

  f32x4 acc[4][4] = {};

  for (int k0 = 0; k0 < 512; k0 += 32) {
    __syncthreads();
    #pragma unroll
    for (int it = 0; it < 2; ++it) {
      const int flat = (it * 256 + tid) * 16;       // byte offset in 8KB tile
      const int row  = flat >> 6;                   // 64 B per row
      const int swc  = (flat >> 4) & 3;
      const int gc   = (swc - (row >> 1)) & 3;      // un-swizzle for global side
      gl_lds16((const char*)A + (size_t)(m0 + row) * 1024 + k0 * 2 + gc * 16,
               (char*)As + flat);
      gl_lds16((const char*)W + (size_t)(n0 + row) * 1024 + k0 * 2 + gc * 16,
               (char*)Bs + flat);
    }
    __syncthreads();

    bf16x8 af[4], bf[4];
    #pragma unroll
    for (int mt = 0; mt < 4; ++mt) {
      const int row = wm + mt * 16 + r;
      const int sw  = (qd + (row >> 1)) & 3;
      af[mt] = *(const bf16x8*)((const char*)As + row * 64 + sw * 16);
    }
    #pragma unroll
    for (int nt = 0; nt < 4; ++nt) {
      const int row = wn + nt * 16 + r;
      const int sw  = (qd + (row >> 1)) & 3;
      bf[nt] = *(const bf16x8*)((const char*)Bs + row * 64 + sw * 16);
    }
    #pragma unroll
    for (int mt = 0; mt < 4; ++mt)
      #pragma unroll
      for (int nt = 0; nt < 4; ++nt)
        acc[mt][nt] = MFMA16(af[mt], bf[nt], acc[mt][nt]);
  }

  float bv[4];
  #pragma unroll
  for (int nt = 0; nt < 4; ++nt) bv[nt] = bs[n0 + wn + nt * 16 + r];

  if (qkv_mode) {
    #pragma unroll
    for (int mt = 0; mt < 4; ++mt) {
      #pragma unroll
      for (int rr = 0; rr < 4; ++rr) {
        const int m   = m0 + wm + mt * 16 + qd * 4 + rr;   // (b*T+t)*C + c
        const int b   = m / 1536;
        const int rem = m - b * 1536;
        const int t   = rem / 6;
        const int c   = rem - t * 6;
        #pragma unroll
        for (int nt = 0; nt < 4; ++nt) {
          const int f = n0 + wn + nt * 16 + r;             // h*64 + d
          const int hh = f >> 6;
          const int d = f & 63;
          const size_t addr = ((((size_t)b * 8 + hh) * 6 + c) * 256 + t) * 64 + d;
          O[addr] = f2b(acc[mt][nt][rr] + bv[nt]);
        }
      }
    }
  } else {
    #pragma unroll
    for (int mt = 0; mt < 4; ++mt) {
      #pragma unroll
      for (int rr = 0; rr < 4; ++rr) {
        const int m = m0 + wm + mt * 16 + qd * 4 + rr;
        #pragma unroll
        for (int nt = 0; nt < 4; ++nt) {
          const int f = n0 + wn + nt * 16 + r;
          OF[(size_t)m * 512 + f] = acc[mt][nt][rr] + bv[nt];   // fp32 output
        }
      }
    }
  }
}

// ---------------------------------------------------------------------------
extern "C" void kernel_launch(void* const* d_in, const int* in_sizes, int n_in,
                              void* d_out, int out_size, void* d_ws, size_t ws_size,
                              hipStream_t stream) {
  const float* x  = (const float*)d_in[0];
  const float* Wq = (const float*)d_in[1];
  const float* bq = (const float*)d_in[2];
  const float* Wk = (const float*)d_in[3];
  const float* bk = (const float*)d_in[4];
  const float* Wv = (const float*)d_in[5];
  const float* bv = (const float*)d_in[6];
  const float* Wp = (const float*)d_in[7];
  const float* bp = (const float*)d_in[8];
  float* out = (float*)d_out;                        // fp32 output

  const size_t PER_B = 256 * 6 * 512;       // 786432 elems per tensor per batch
  const size_t WSEG  = 4 * 262144;          // converted weights: Wq,Wk,Wv,Wp

  int NB = 16;
  while (NB > 1 && (WSEG + (size_t)2 * NB * PER_B) * 2 > ws_size) NB >>= 1;

  u16* wbf = (u16*)d_ws;                    // Wq | Wk | Wv | Wp (bf16)
  u16* Wpb = wbf + 3 * 262144;

  const size_t slab = (size_t)NB * PER_B;
  u16* xbf  = wbf + WSEG;
  u16* y_ws = xbf + slab;

  cvt_w<<<dim3(256, 4), 256, 0, stream>>>(Wq, Wk, Wv, Wp, wbf);

  const int nslab = 16 / NB;
  for (int s = 0; s < nslab; ++s) {
    const float* x_s  = x   + (size_t)s * NB * PER_B;
    float*      out_s = out + (size_t)s * NB * PER_B;
    cvt_x<<<dim3(NB * 768), 256, 0, stream>>>(x_s, xbf);
    qkv_attn<<<dim3(NB * 48), 512, 0, stream>>>(xbf, wbf, bq, bk, bv, y_ws);
    gemm_bt<<<dim3(NB * 12, 4, 1), 256, 0, stream>>>(
        y_ws, Wpb, Wpb, Wpb, bp, bp, bp, nullptr, nullptr, nullptr, out_s, 0);
  }
}